// Round 11
// baseline (881.903 us; speedup 1.0000x reference)
//
#include <hip/hip_runtime.h>
#include <cstddef>

#define BB    16
#define CDIM  512
#define HWN   784
#define KC    2048
#define NR    (BB*HWN)                  // 12544 rows (= 49*256)
#define ETOT  ((size_t)BB*CDIM*HWN)     // 6422528 elements per tensor
#define NSTRIP 16                       // code strips of 128
#define TAU   0.02f
#define APL   8192                      // A plane buffer (halves) = 256*32
#define BPL   4096                      // B plane buffer (halves) = 128*32

typedef _Float16 hf8 __attribute__((ext_vector_type(8)));
typedef float f32x4 __attribute__((ext_vector_type(4)));

__device__ __forceinline__ void gload_lds16(const void* g, void* l) {
    __builtin_amdgcn_global_load_lds((const __attribute__((address_space(1))) void*)g,
                                     (__attribute__((address_space(3))) void*)l, 16, 0, 0);
}

// ---------------------------------------------------------------- utilities

// head (B,C,HW) -> f rows (fp32) AND fs split rows (f16 [hi(512)|lo(512)]);
// block (0,0,0) also zeroes the loss accumulators.
__global__ __launch_bounds__(256)
void transpose_head_split(const float* __restrict__ head, float* __restrict__ f,
                          _Float16* __restrict__ fs, float* __restrict__ lacc) {
    __shared__ float tile[32][33];
    int b = blockIdx.z, c0 = blockIdx.y * 32, h0 = blockIdx.x * 32;
    int t = threadIdx.x;
    if (b == 0 && blockIdx.y == 0 && blockIdx.x == 0 && t < 3) lacc[t] = 0.f;
    const float* src = head + (size_t)b * CDIM * HWN;
    {
        int hl = t & 31, cl0 = t >> 5;
#pragma unroll
        for (int it = 0; it < 4; ++it) {
            int cl = cl0 + it * 8;
            int hw = h0 + hl;
            if (hw < HWN) tile[cl][hl] = src[(size_t)(c0 + cl) * HWN + hw];
        }
    }
    __syncthreads();
    float* dst = f + (size_t)b * HWN * CDIM;
    _Float16* dsts = fs + (size_t)b * HWN * 1024;
    {
        int cl = t & 31, hl0 = t >> 5;
#pragma unroll
        for (int it = 0; it < 4; ++it) {
            int hl = hl0 + it * 8;
            int hw = h0 + hl;
            if (hw < HWN) {
                float v = tile[cl][hl];
                dst[(size_t)hw * CDIM + c0 + cl] = v;
                _Float16 h = (_Float16)v;
                dsts[(size_t)hw * 1024 + c0 + cl] = h;
                dsts[(size_t)hw * 1024 + 512 + c0 + cl] = (_Float16)(v - (float)h);
            }
        }
    }
}

// codebook fp32 [K][512] -> f16 split [K][1024] + ||row||^2 (one wave per row)
__global__ __launch_bounds__(256)
void split_code_norm(const float* __restrict__ src, _Float16* __restrict__ dst,
                     float* __restrict__ cnorm) {
    int tid = blockIdx.x * 256 + threadIdx.x;        // 8 elems per thread
    int row = tid >> 6, c8 = (tid & 63) * 8;
    const float* p = src + (size_t)row * CDIM + c8;
    float4 v0 = *(const float4*)p, v1 = *(const float4*)(p + 4);
    hf8 hi, lo;
    float x[8] = {v0.x, v0.y, v0.z, v0.w, v1.x, v1.y, v1.z, v1.w};
    float s = 0.f;
#pragma unroll
    for (int j = 0; j < 8; ++j) {
        _Float16 h = (_Float16)x[j];
        hi[j] = h;
        lo[j] = (_Float16)(x[j] - (float)h);
        s += x[j] * x[j];
    }
    *(hf8*)&dst[(size_t)row * 1024 + c8] = hi;
    *(hf8*)&dst[(size_t)row * 1024 + 512 + c8] = lo;
#pragma unroll
    for (int off = 32; off; off >>= 1) s += __shfl_down(s, off);
    if ((threadIdx.x & 63) == 0) cnorm[row] = s;
}

// --------------------------------------------------- MFMA argmin (3-plane)
// 256 rows x 128 codes per block, 512 threads = 8 waves (4x2 of 64x64).
// DOUBLE-buffered DMA staging with COUNTED vmcnt (T3/T4): per chunk, issue
// next chunk's 6 loads into buf^1, wait vmcnt(6) (current chunk landed, next
// stays in flight), raw s_barrier, MFMA, end barrier. grid (16, 49).
__global__ __launch_bounds__(512, 2)
void argmin_fast(const _Float16* __restrict__ fs, const _Float16* __restrict__ cs,
                 const float* __restrict__ cnorm, float4* __restrict__ part) {
    __shared__ _Float16 Ah[2 * APL];
    __shared__ _Float16 Al[2 * APL];
    __shared__ _Float16 Bh[2 * BPL];
    __shared__ _Float16 Bl[2 * BPL];

    int t = threadIdx.x;
    int lane = t & 63, w = t >> 6;
    int wr = w >> 1, wc = w & 1;
    int rb = blockIdx.y * 256, cb = blockIdx.x * 128;

    // staging: A planes rows t>>2 and 128+(t>>2) (granules t, 512+t),
    // B planes row t>>2 (granule t). LDS dest linear; source XOR-swizzled.
    int r1 = t >> 2, s1 = t & 3;
    int sg = s1 ^ ((r1 >> 1) & 3);           // (r+128)>>1 & 3 identical
    const _Float16* gA1 = fs + (size_t)(rb + r1) * 1024 + sg * 8;
    const _Float16* gA2 = fs + (size_t)(rb + 128 + r1) * 1024 + sg * 8;
    const _Float16* gB1 = cs + (size_t)(cb + r1) * 1024 + sg * 8;
    int d1 = t * 8, d2 = (512 + t) * 8;

    // fragment read addressing (plane-local); 16-row steps keep (row>>1)&3
    int frA = wr * 64 + (lane & 15);
    int frB = wc * 64 + (lane & 15);
    int fslot = lane >> 4;
    int oA = frA * 32 + (fslot ^ ((frA >> 1) & 3)) * 8;
    int oB = frB * 32 + (fslot ^ ((frB >> 1) & 3)) * 8;

    f32x4 acc[4][4];
#pragma unroll
    for (int m = 0; m < 4; ++m)
#pragma unroll
        for (int n = 0; n < 4; ++n) acc[m][n] = (f32x4)0.f;

#define STAGE(P, KK) do {                                                   \
        int _ko = (KK) * 32;                                                \
        int _ba = (P) * APL, _bb = (P) * BPL;                               \
        gload_lds16(gA1 + _ko,       &Ah[_ba + d1]);                        \
        gload_lds16(gA2 + _ko,       &Ah[_ba + d2]);                        \
        gload_lds16(gA1 + _ko + 512, &Al[_ba + d1]);                        \
        gload_lds16(gA2 + _ko + 512, &Al[_ba + d2]);                        \
        gload_lds16(gB1 + _ko,       &Bh[_bb + d1]);                        \
        gload_lds16(gB1 + _ko + 512, &Bl[_bb + d1]);                        \
    } while (0)

    STAGE(0, 0);
    for (int kk = 0; kk < 16; ++kk) {
        int ba = (kk & 1) * APL, bb = (kk & 1) * BPL;
        if (kk < 15) {
            STAGE((kk + 1) & 1, kk + 1);     // next chunk: stays in flight
            asm volatile("s_waitcnt vmcnt(6)" ::: "memory");  // cur landed
        } else {
            asm volatile("s_waitcnt vmcnt(0)" ::: "memory");
        }
        __builtin_amdgcn_s_barrier();        // all waves: cur chunk resident
        __builtin_amdgcn_sched_barrier(0);
        hf8 bh[4], bl[4];
#pragma unroll
        for (int n = 0; n < 4; ++n) {
            bh[n] = *(hf8*)&Bh[bb + oB + n * 512];
            bl[n] = *(hf8*)&Bl[bb + oB + n * 512];
        }
#pragma unroll
        for (int m = 0; m < 4; ++m) {
            hf8 ah = *(hf8*)&Ah[ba + oA + m * 512];
            hf8 al = *(hf8*)&Al[ba + oA + m * 512];
#pragma unroll
            for (int n = 0; n < 4; ++n) {
                acc[m][n] = __builtin_amdgcn_mfma_f32_16x16x32_f16(ah, bh[n], acc[m][n], 0, 0, 0);
                acc[m][n] = __builtin_amdgcn_mfma_f32_16x16x32_f16(ah, bl[n], acc[m][n], 0, 0, 0);
                acc[m][n] = __builtin_amdgcn_mfma_f32_16x16x32_f16(al, bh[n], acc[m][n], 0, 0, 0);
            }
        }
        __builtin_amdgcn_sched_barrier(0);
        __builtin_amdgcn_s_barrier();        // reads done: buffer reusable
    }
#undef STAGE

    // epilogue: msm aliased into Ah (all LDS reads done; barrier above).
    float4 (*msm)[2] = (float4(*)[2])Ah;

    // per-lane top-2 over n, butterfly over 16 cols, deposit per (row, wc).
    // D layout: col = lane&15, row = (lane>>4)*4 + i.
    int g = lane >> 4;
#pragma unroll
    for (int m = 0; m < 4; ++m)
#pragma unroll
        for (int i = 0; i < 4; ++i) {
            float v1 = 3.0e38f, v2 = 3.0e38f;
            int i1 = 0x7fffffff, i2 = 0x7fffffff;
#pragma unroll
            for (int n = 0; n < 4; ++n) {
                int kcode = cb + wc * 64 + n * 16 + (lane & 15);
                float d = fmaf(-2.f, acc[m][n][i], cnorm[kcode]);
                if (d < v1) { v2 = v1; i2 = i1; v1 = d; i1 = kcode; }
                else if (d < v2) { v2 = d; i2 = kcode; }
            }
#pragma unroll
            for (int off = 1; off < 16; off <<= 1) {
                float ov1 = __shfl_xor(v1, off, 64); int oi1 = __shfl_xor(i1, off, 64);
                float ov2 = __shfl_xor(v2, off, 64); int oi2 = __shfl_xor(i2, off, 64);
                if (ov1 < v1 || (ov1 == v1 && oi1 < i1)) {
                    float tv = v1; int ti = i1;
                    v1 = ov1; i1 = oi1; ov1 = tv; oi1 = ti;
                }
                if (ov1 < v2 || (ov1 == v2 && oi1 < i2)) { v2 = ov1; i2 = oi1; }
                if (ov2 < v2 || (ov2 == v2 && oi2 < i2)) { v2 = ov2; i2 = oi2; }
            }
            if ((lane & 15) == 0)
                msm[wr * 64 + m * 16 + g * 4 + i][wc] =
                    make_float4(v1, __int_as_float(i1), v2, __int_as_float(i2));
        }
    __syncthreads();
    if (t < 256) {
        float4 q0 = msm[t][0], q1 = msm[t][1];
        float v1 = q0.x, v2 = q0.z;
        int   i1 = __float_as_int(q0.y), i2 = __float_as_int(q0.w);
        float ov1 = q1.x, ov2 = q1.z;
        int   oi1 = __float_as_int(q1.y), oi2 = __float_as_int(q1.w);
        if (ov1 < v1 || (ov1 == v1 && oi1 < i1)) {
            float tv = v1; int ti = i1;
            v1 = ov1; i1 = oi1; ov1 = tv; oi1 = ti;
        }
        if (ov1 < v2 || (ov1 == v2 && oi1 < i2)) { v2 = ov1; i2 = oi1; }
        if (ov2 < v2 || (ov2 == v2 && oi2 < i2)) { v2 = ov2; i2 = oi2; }
        part[(size_t)blockIdx.x * NR + rb + t] =
            make_float4(v1, __int_as_float(i1), v2, __int_as_float(i2));
    }
}

// combine NSTRIP partials per row; fp64 re-check when top-2 gap < TAU
__global__ __launch_bounds__(256)
void combine_fix(const float4* __restrict__ part, const float* __restrict__ f,
                 const float* __restrict__ code, int* __restrict__ idx) {
    int n = blockIdx.x * 256 + threadIdx.x;
    if (n >= NR) return;
    float bv1 = 3.0e38f, bv2 = 3.0e38f;
    int bi1 = 0x7fffffff, bi2 = 0x7fffffff;
    for (int p = 0; p < NSTRIP; ++p) {
        float4 q = part[(size_t)p * NR + n];
        float ov1 = q.x, ov2 = q.z;
        int oi1 = __float_as_int(q.y), oi2 = __float_as_int(q.w);
        if (ov1 < bv1 || (ov1 == bv1 && oi1 < bi1)) {
            float tv = bv1; int ti = bi1;
            bv1 = ov1; bi1 = oi1; ov1 = tv; oi1 = ti;
        }
        if (ov1 < bv2 || (ov1 == bv2 && oi1 < bi2)) { bv2 = ov1; bi2 = oi1; }
        if (ov2 < bv2 || (ov2 == bv2 && oi2 < bi2)) { bv2 = ov2; bi2 = oi2; }
    }
    bi1 = min(max(bi1, 0), KC - 1);
    bi2 = min(max(bi2, 0), KC - 1);
    if (bv2 - bv1 < TAU) {
        const float* fr = f + (size_t)n * CDIM;
        const float* ca = code + (size_t)bi1 * CDIM;
        const float* cb = code + (size_t)bi2 * CDIM;
        double d1 = 0.0, d2 = 0.0;
        for (int j = 0; j < CDIM; ++j) {
            double fv = fr[j], av = ca[j], bv = cb[j];
            d1 += av * av - 2.0 * fv * av;
            d2 += bv * bv - 2.0 * fv * bv;
        }
        if (d2 < d1 || (d2 == d1 && bi2 < bi1)) bi1 = bi2;
    }
    idx[n] = bi1;
}

// ------------------------------------------------------------ update stage
// Also emits f16 split of the new residual (next stage's argmin input).
__global__ __launch_bounds__(256)
void vq_update(float* __restrict__ f, const float* __restrict__ code,
               const int* __restrict__ idx, float* __restrict__ xout,
               const float* __restrict__ x1p, const float* __restrict__ x2p,
               float* __restrict__ reconp, _Float16* __restrict__ fsout,
               float* __restrict__ lacc) {
    __shared__ float qt[32][33];
    __shared__ float wsum[4];
    int b = blockIdx.z, c0 = blockIdx.y * 32, h0 = blockIdx.x * 32;
    int t = threadIdx.x;
    int tx = t & 31, ty0 = t >> 5;
    float lsum = 0.f;
#pragma unroll
    for (int it = 0; it < 4; ++it) {
        int hwl = ty0 + it * 8;
        int hw = h0 + hwl;
        float qv = 0.f;
        if (hw < HWN) {
            int n = b * HWN + hw;
            size_t fo = (size_t)n * CDIM + c0 + tx;
            float fv = f[fo];
            qv = code[(size_t)idx[n] * CDIM + c0 + tx];
            float rem = fv - qv;
            f[fo] = rem;
            lsum += rem * rem;
            if (fsout) {
                _Float16 h = (_Float16)rem;
                fsout[(size_t)n * 1024 + c0 + tx] = h;
                fsout[(size_t)n * 1024 + 512 + c0 + tx] = (_Float16)(rem - (float)h);
            }
        }
        qt[tx][hwl] = qv;
    }
    __syncthreads();
    {
        int hl = t & 31, cl0 = t >> 5;
#pragma unroll
        for (int it = 0; it < 4; ++it) {
            int cl = cl0 + it * 8;
            int hw = h0 + hl;
            if (hw < HWN) {
                size_t off = ((size_t)b * CDIM + c0 + cl) * HWN + hw;
                float qv = qt[cl][hl];
                xout[off] = qv;
                if (reconp) reconp[off] = qv + x1p[off] + x2p[off];
            }
        }
    }
#pragma unroll
    for (int off = 32; off; off >>= 1) lsum += __shfl_down(lsum, off);
    int lane = t & 63, w = t >> 6;
    if (lane == 0) wsum[w] = lsum;
    __syncthreads();
    if (t == 0) atomicAdd(lacc, wsum[0] + wsum[1] + wsum[2] + wsum[3]);
}

__global__ void finalize_losses(const float* __restrict__ lacc, float* __restrict__ out) {
    int t = threadIdx.x;
    if (t < 3) out[t] = 2.0f * lacc[t] / (float)ETOT;
}

// ------------------------------------------------------------------- launch

extern "C" void kernel_launch(void* const* d_in, const int* in_sizes, int n_in,
                              void* d_out, int out_size, void* d_ws, size_t ws_size,
                              hipStream_t stream) {
    (void)in_sizes; (void)n_in; (void)out_size; (void)ws_size;
    const float* head = (const float*)d_in[0];
    const float* cbs[3] = {(const float*)d_in[1], (const float*)d_in[2], (const float*)d_in[3]};
    float* out = (float*)d_out;
    char* ws = (char*)d_ws;

    size_t o_f = 0;
    size_t o_fs   = o_f   + ETOT * 4;
    size_t o_cs   = o_fs  + (size_t)NR * 1024 * 2;
    size_t o_part = o_cs  + (size_t)KC * 1024 * 2;
    size_t o_idx  = o_part + (size_t)NSTRIP * NR * 16;
    size_t o_cn   = o_idx + (size_t)NR * 4;
    size_t o_la   = o_cn  + (size_t)KC * 4;      // total ~58.85 MB (proven fits, R6)

    float*     f     = (float*)(ws + o_f);
    _Float16*  fs    = (_Float16*)(ws + o_fs);
    _Float16*  cspl  = (_Float16*)(ws + o_cs);
    float4*    part  = (float4*)(ws + o_part);
    int*       idx   = (int*)(ws + o_idx);
    float*     cnorm = (float*)(ws + o_cn);
    float*     lacc  = (float*)(ws + o_la);

    transpose_head_split<<<dim3(25, 16, 16), 256, 0, stream>>>(head, f, fs, lacc);
    for (int s = 0; s < 3; ++s) {
        split_code_norm<<<dim3(KC * 64 / 256), 256, 0, stream>>>(cbs[s], cspl, cnorm);
        argmin_fast<<<dim3(NSTRIP, 49), 512, 0, stream>>>(fs, cspl, cnorm, part);
        combine_fix<<<dim3((NR + 255) / 256), 256, 0, stream>>>(part, f, cbs[s], idx);
        float* xout   = out + (size_t)s * ETOT;
        float* reconp = (s == 2) ? out + 3 * ETOT + 3 : nullptr;
        _Float16* fsout = (s < 2) ? fs : nullptr;
        vq_update<<<dim3(25, 16, 16), 256, 0, stream>>>(f, cbs[s], idx, xout,
                                                        out, out + ETOT, reconp,
                                                        fsout, lacc + s);
    }
    finalize_losses<<<1, 64, 0, stream>>>(lacc, out + 3 * ETOT);
}

// Round 12
// 738.450 us; speedup vs baseline: 1.1943x; 1.1943x over previous
//
#include <hip/hip_runtime.h>
#include <cstddef>

#define BB    16
#define CDIM  512
#define HWN   784
#define KC    2048
#define NR    (BB*HWN)                  // 12544 rows (= 49*256)
#define ETOT  ((size_t)BB*CDIM*HWN)     // 6422528 elements per tensor
#define NSTRIP 16                       // code strips of 128
#define TAU   0.02f
#define APL   8192                      // A plane buffer (halves) = 256*32
#define BPL   4096                      // B plane buffer (halves) = 128*32

typedef _Float16 hf8 __attribute__((ext_vector_type(8)));
typedef float f32x4 __attribute__((ext_vector_type(4)));

__device__ __forceinline__ void gload_lds16(const void* g, void* l) {
    __builtin_amdgcn_global_load_lds((const __attribute__((address_space(1))) void*)g,
                                     (__attribute__((address_space(3))) void*)l, 16, 0, 0);
}

// ---------------------------------------------------------------- utilities

// head (B,C,HW) -> f rows (fp32) AND fs split rows (f16 [hi(512)|lo(512)]);
// block (0,0,0) also zeroes the loss accumulators.
__global__ __launch_bounds__(256)
void transpose_head_split(const float* __restrict__ head, float* __restrict__ f,
                          _Float16* __restrict__ fs, float* __restrict__ lacc) {
    __shared__ float tile[32][33];
    int b = blockIdx.z, c0 = blockIdx.y * 32, h0 = blockIdx.x * 32;
    int t = threadIdx.x;
    if (b == 0 && blockIdx.y == 0 && blockIdx.x == 0 && t < 3) lacc[t] = 0.f;
    const float* src = head + (size_t)b * CDIM * HWN;
    {
        int hl = t & 31, cl0 = t >> 5;
#pragma unroll
        for (int it = 0; it < 4; ++it) {
            int cl = cl0 + it * 8;
            int hw = h0 + hl;
            if (hw < HWN) tile[cl][hl] = src[(size_t)(c0 + cl) * HWN + hw];
        }
    }
    __syncthreads();
    float* dst = f + (size_t)b * HWN * CDIM;
    _Float16* dsts = fs + (size_t)b * HWN * 1024;
    {
        int cl = t & 31, hl0 = t >> 5;
#pragma unroll
        for (int it = 0; it < 4; ++it) {
            int hl = hl0 + it * 8;
            int hw = h0 + hl;
            if (hw < HWN) {
                float v = tile[cl][hl];
                dst[(size_t)hw * CDIM + c0 + cl] = v;
                _Float16 h = (_Float16)v;
                dsts[(size_t)hw * 1024 + c0 + cl] = h;
                dsts[(size_t)hw * 1024 + 512 + c0 + cl] = (_Float16)(v - (float)h);
            }
        }
    }
}

// codebook fp32 [K][512] -> f16 split [K][1024] + ||row||^2 (one wave per row)
__global__ __launch_bounds__(256)
void split_code_norm(const float* __restrict__ src, _Float16* __restrict__ dst,
                     float* __restrict__ cnorm) {
    int tid = blockIdx.x * 256 + threadIdx.x;        // 8 elems per thread
    int row = tid >> 6, c8 = (tid & 63) * 8;
    const float* p = src + (size_t)row * CDIM + c8;
    float4 v0 = *(const float4*)p, v1 = *(const float4*)(p + 4);
    hf8 hi, lo;
    float x[8] = {v0.x, v0.y, v0.z, v0.w, v1.x, v1.y, v1.z, v1.w};
    float s = 0.f;
#pragma unroll
    for (int j = 0; j < 8; ++j) {
        _Float16 h = (_Float16)x[j];
        hi[j] = h;
        lo[j] = (_Float16)(x[j] - (float)h);
        s += x[j] * x[j];
    }
    *(hf8*)&dst[(size_t)row * 1024 + c8] = hi;
    *(hf8*)&dst[(size_t)row * 1024 + 512 + c8] = lo;
#pragma unroll
    for (int off = 32; off; off >>= 1) s += __shfl_down(s, off);
    if ((threadIdx.x & 63) == 0) cnorm[row] = s;
}

// --------------------------------------------------- MFMA argmin (3-plane)
// 256 rows x 128 codes per block, 512 threads = 8 waves (4x2 of 64x64).
// A (slow operand, L3/HBM) DOUBLE-buffered with counted vmcnt(4) — its 4
// loads stay in flight across the whole compute phase. B (L2-hot codebook
// strip) single-buffered, latency exposed (~200cy only). LDS exactly 80KB
// -> 2 blocks/CU. XCD-swizzled 1-D grid of 784 (=8*98). T5 setprio on MFMA.
__global__ __launch_bounds__(512, 4)
void argmin_fast(const _Float16* __restrict__ fs, const _Float16* __restrict__ cs,
                 const float* __restrict__ cnorm, float4* __restrict__ part) {
    __shared__ _Float16 Ah[2 * APL];
    __shared__ _Float16 Al[2 * APL];
    __shared__ _Float16 Bh[BPL];
    __shared__ _Float16 Bl[BPL];

    int t = threadIdx.x;
    int lane = t & 63, w = t >> 6;
    int wr = w >> 1, wc = w & 1;

    // XCD-aware swizzle: nwg=784=8*98, bijective chunked map (m157)
    int lin = blockIdx.x;
    int swz = (lin & 7) * 98 + (lin >> 3);
    int strip = swz & 15, rowtile = swz >> 4;
    int rb = rowtile * 256, cb = strip * 128;

    // staging: A planes rows t>>2 and 128+(t>>2) (granules t, 512+t),
    // B planes row t>>2 (granule t). LDS dest linear; source XOR-swizzled.
    int r1 = t >> 2, s1 = t & 3;
    int sg = s1 ^ ((r1 >> 1) & 3);           // (r+128)>>1 & 3 identical
    const _Float16* gA1 = fs + (size_t)(rb + r1) * 1024 + sg * 8;
    const _Float16* gA2 = fs + (size_t)(rb + 128 + r1) * 1024 + sg * 8;
    const _Float16* gB1 = cs + (size_t)(cb + r1) * 1024 + sg * 8;
    int d1 = t * 8, d2 = (512 + t) * 8;

    // fragment read addressing (plane-local); 16-row steps keep (row>>1)&3
    int frA = wr * 64 + (lane & 15);
    int frB = wc * 64 + (lane & 15);
    int fslot = lane >> 4;
    int oA = frA * 32 + (fslot ^ ((frA >> 1) & 3)) * 8;
    int oB = frB * 32 + (fslot ^ ((frB >> 1) & 3)) * 8;

    f32x4 acc[4][4];
#pragma unroll
    for (int m = 0; m < 4; ++m)
#pragma unroll
        for (int n = 0; n < 4; ++n) acc[m][n] = (f32x4)0.f;

#define STAGE_A(P, KK) do {                                                 \
        int _ko = (KK) * 32, _ba = (P) * APL;                               \
        gload_lds16(gA1 + _ko,       &Ah[_ba + d1]);                        \
        gload_lds16(gA2 + _ko,       &Ah[_ba + d2]);                        \
        gload_lds16(gA1 + _ko + 512, &Al[_ba + d1]);                        \
        gload_lds16(gA2 + _ko + 512, &Al[_ba + d2]);                        \
    } while (0)
#define STAGE_B(KK) do {                                                    \
        int _ko = (KK) * 32;                                                \
        gload_lds16(gB1 + _ko,       &Bh[d1]);                              \
        gload_lds16(gB1 + _ko + 512, &Bl[d1]);                              \
    } while (0)

    STAGE_A(0, 0);
    for (int kk = 0; kk < 16; ++kk) {
        int ba = (kk & 1) * APL;
        STAGE_B(kk);                         // B buffer free (prev end-barrier)
        if (kk < 15) {
            STAGE_A((kk + 1) & 1, kk + 1);   // A(kk+1): stays in flight
            asm volatile("s_waitcnt vmcnt(4)" ::: "memory");  // A(kk),B(kk) done
        } else {
            asm volatile("s_waitcnt vmcnt(0)" ::: "memory");
        }
        __builtin_amdgcn_s_barrier();        // all waves: cur chunk resident
        __builtin_amdgcn_sched_barrier(0);
        hf8 bh[4], bl[4];
#pragma unroll
        for (int n = 0; n < 4; ++n) {
            bh[n] = *(hf8*)&Bh[oB + n * 512];
            bl[n] = *(hf8*)&Bl[oB + n * 512];
        }
        __builtin_amdgcn_s_setprio(1);
#pragma unroll
        for (int m = 0; m < 4; ++m) {
            hf8 ah = *(hf8*)&Ah[ba + oA + m * 512];
            hf8 al = *(hf8*)&Al[ba + oA + m * 512];
#pragma unroll
            for (int n = 0; n < 4; ++n) {
                acc[m][n] = __builtin_amdgcn_mfma_f32_16x16x32_f16(ah, bh[n], acc[m][n], 0, 0, 0);
                acc[m][n] = __builtin_amdgcn_mfma_f32_16x16x32_f16(ah, bl[n], acc[m][n], 0, 0, 0);
                acc[m][n] = __builtin_amdgcn_mfma_f32_16x16x32_f16(al, bh[n], acc[m][n], 0, 0, 0);
            }
        }
        __builtin_amdgcn_s_setprio(0);
        __builtin_amdgcn_sched_barrier(0);
        __builtin_amdgcn_s_barrier();        // reads done: buffers reusable
    }
#undef STAGE_A
#undef STAGE_B

    // epilogue: msm aliased into Ah (all LDS reads done; barrier above).
    float4 (*msm)[2] = (float4(*)[2])Ah;

    // per-lane top-2 over n, butterfly over 16 cols, deposit per (row, wc).
    // D layout: col = lane&15, row = (lane>>4)*4 + i.
    int g = lane >> 4;
#pragma unroll
    for (int m = 0; m < 4; ++m)
#pragma unroll
        for (int i = 0; i < 4; ++i) {
            float v1 = 3.0e38f, v2 = 3.0e38f;
            int i1 = 0x7fffffff, i2 = 0x7fffffff;
#pragma unroll
            for (int n = 0; n < 4; ++n) {
                int kcode = cb + wc * 64 + n * 16 + (lane & 15);
                float d = fmaf(-2.f, acc[m][n][i], cnorm[kcode]);
                if (d < v1) { v2 = v1; i2 = i1; v1 = d; i1 = kcode; }
                else if (d < v2) { v2 = d; i2 = kcode; }
            }
#pragma unroll
            for (int off = 1; off < 16; off <<= 1) {
                float ov1 = __shfl_xor(v1, off, 64); int oi1 = __shfl_xor(i1, off, 64);
                float ov2 = __shfl_xor(v2, off, 64); int oi2 = __shfl_xor(i2, off, 64);
                if (ov1 < v1 || (ov1 == v1 && oi1 < i1)) {
                    float tv = v1; int ti = i1;
                    v1 = ov1; i1 = oi1; ov1 = tv; oi1 = ti;
                }
                if (ov1 < v2 || (ov1 == v2 && oi1 < i2)) { v2 = ov1; i2 = oi1; }
                if (ov2 < v2 || (ov2 == v2 && oi2 < i2)) { v2 = ov2; i2 = oi2; }
            }
            if ((lane & 15) == 0)
                msm[wr * 64 + m * 16 + g * 4 + i][wc] =
                    make_float4(v1, __int_as_float(i1), v2, __int_as_float(i2));
        }
    __syncthreads();
    if (t < 256) {
        float4 q0 = msm[t][0], q1 = msm[t][1];
        float v1 = q0.x, v2 = q0.z;
        int   i1 = __float_as_int(q0.y), i2 = __float_as_int(q0.w);
        float ov1 = q1.x, ov2 = q1.z;
        int   oi1 = __float_as_int(q1.y), oi2 = __float_as_int(q1.w);
        if (ov1 < v1 || (ov1 == v1 && oi1 < i1)) {
            float tv = v1; int ti = i1;
            v1 = ov1; i1 = oi1; ov1 = tv; oi1 = ti;
        }
        if (ov1 < v2 || (ov1 == v2 && oi1 < i2)) { v2 = ov1; i2 = oi1; }
        if (ov2 < v2 || (ov2 == v2 && oi2 < i2)) { v2 = ov2; i2 = oi2; }
        part[(size_t)strip * NR + rb + t] =
            make_float4(v1, __int_as_float(i1), v2, __int_as_float(i2));
    }
}

// combine NSTRIP partials per row; fp64 re-check when top-2 gap < TAU
__global__ __launch_bounds__(256)
void combine_fix(const float4* __restrict__ part, const float* __restrict__ f,
                 const float* __restrict__ code, int* __restrict__ idx) {
    int n = blockIdx.x * 256 + threadIdx.x;
    if (n >= NR) return;
    float bv1 = 3.0e38f, bv2 = 3.0e38f;
    int bi1 = 0x7fffffff, bi2 = 0x7fffffff;
    for (int p = 0; p < NSTRIP; ++p) {
        float4 q = part[(size_t)p * NR + n];
        float ov1 = q.x, ov2 = q.z;
        int oi1 = __float_as_int(q.y), oi2 = __float_as_int(q.w);
        if (ov1 < bv1 || (ov1 == bv1 && oi1 < bi1)) {
            float tv = bv1; int ti = bi1;
            bv1 = ov1; bi1 = oi1; ov1 = tv; oi1 = ti;
        }
        if (ov1 < bv2 || (ov1 == bv2 && oi1 < bi2)) { bv2 = ov1; bi2 = oi1; }
        if (ov2 < bv2 || (ov2 == bv2 && oi2 < bi2)) { bv2 = ov2; bi2 = oi2; }
    }
    bi1 = min(max(bi1, 0), KC - 1);
    bi2 = min(max(bi2, 0), KC - 1);
    if (bv2 - bv1 < TAU) {
        const float* fr = f + (size_t)n * CDIM;
        const float* ca = code + (size_t)bi1 * CDIM;
        const float* cb = code + (size_t)bi2 * CDIM;
        double d1 = 0.0, d2 = 0.0;
        for (int j = 0; j < CDIM; ++j) {
            double fv = fr[j], av = ca[j], bv = cb[j];
            d1 += av * av - 2.0 * fv * av;
            d2 += bv * bv - 2.0 * fv * bv;
        }
        if (d2 < d1 || (d2 == d1 && bi2 < bi1)) bi1 = bi2;
    }
    idx[n] = bi1;
}

// ------------------------------------------------------------ update stage
// Also emits f16 split of the new residual (next stage's argmin input).
__global__ __launch_bounds__(256)
void vq_update(float* __restrict__ f, const float* __restrict__ code,
               const int* __restrict__ idx, float* __restrict__ xout,
               const float* __restrict__ x1p, const float* __restrict__ x2p,
               float* __restrict__ reconp, _Float16* __restrict__ fsout,
               float* __restrict__ lacc) {
    __shared__ float qt[32][33];
    __shared__ float wsum[4];
    int b = blockIdx.z, c0 = blockIdx.y * 32, h0 = blockIdx.x * 32;
    int t = threadIdx.x;
    int tx = t & 31, ty0 = t >> 5;
    float lsum = 0.f;
#pragma unroll
    for (int it = 0; it < 4; ++it) {
        int hwl = ty0 + it * 8;
        int hw = h0 + hwl;
        float qv = 0.f;
        if (hw < HWN) {
            int n = b * HWN + hw;
            size_t fo = (size_t)n * CDIM + c0 + tx;
            float fv = f[fo];
            qv = code[(size_t)idx[n] * CDIM + c0 + tx];
            float rem = fv - qv;
            f[fo] = rem;
            lsum += rem * rem;
            if (fsout) {
                _Float16 h = (_Float16)rem;
                fsout[(size_t)n * 1024 + c0 + tx] = h;
                fsout[(size_t)n * 1024 + 512 + c0 + tx] = (_Float16)(rem - (float)h);
            }
        }
        qt[tx][hwl] = qv;
    }
    __syncthreads();
    {
        int hl = t & 31, cl0 = t >> 5;
#pragma unroll
        for (int it = 0; it < 4; ++it) {
            int cl = cl0 + it * 8;
            int hw = h0 + hl;
            if (hw < HWN) {
                size_t off = ((size_t)b * CDIM + c0 + cl) * HWN + hw;
                float qv = qt[cl][hl];
                xout[off] = qv;
                if (reconp) reconp[off] = qv + x1p[off] + x2p[off];
            }
        }
    }
#pragma unroll
    for (int off = 32; off; off >>= 1) lsum += __shfl_down(lsum, off);
    int lane = t & 63, w = t >> 6;
    if (lane == 0) wsum[w] = lsum;
    __syncthreads();
    if (t == 0) atomicAdd(lacc, wsum[0] + wsum[1] + wsum[2] + wsum[3]);
}

__global__ void finalize_losses(const float* __restrict__ lacc, float* __restrict__ out) {
    int t = threadIdx.x;
    if (t < 3) out[t] = 2.0f * lacc[t] / (float)ETOT;
}

// ------------------------------------------------------------------- launch

extern "C" void kernel_launch(void* const* d_in, const int* in_sizes, int n_in,
                              void* d_out, int out_size, void* d_ws, size_t ws_size,
                              hipStream_t stream) {
    (void)in_sizes; (void)n_in; (void)out_size; (void)ws_size;
    const float* head = (const float*)d_in[0];
    const float* cbs[3] = {(const float*)d_in[1], (const float*)d_in[2], (const float*)d_in[3]};
    float* out = (float*)d_out;
    char* ws = (char*)d_ws;

    size_t o_f = 0;
    size_t o_fs   = o_f   + ETOT * 4;
    size_t o_cs   = o_fs  + (size_t)NR * 1024 * 2;
    size_t o_part = o_cs  + (size_t)KC * 1024 * 2;
    size_t o_idx  = o_part + (size_t)NSTRIP * NR * 16;
    size_t o_cn   = o_idx + (size_t)NR * 4;
    size_t o_la   = o_cn  + (size_t)KC * 4;      // total ~58.85 MB (proven fits, R6)

    float*     f     = (float*)(ws + o_f);
    _Float16*  fs    = (_Float16*)(ws + o_fs);
    _Float16*  cspl  = (_Float16*)(ws + o_cs);
    float4*    part  = (float4*)(ws + o_part);
    int*       idx   = (int*)(ws + o_idx);
    float*     cnorm = (float*)(ws + o_cn);
    float*     lacc  = (float*)(ws + o_la);

    transpose_head_split<<<dim3(25, 16, 16), 256, 0, stream>>>(head, f, fs, lacc);
    for (int s = 0; s < 3; ++s) {
        split_code_norm<<<dim3(KC * 64 / 256), 256, 0, stream>>>(cbs[s], cspl, cnorm);
        argmin_fast<<<dim3(NSTRIP * 49), 512, 0, stream>>>(fs, cspl, cnorm, part);
        combine_fix<<<dim3((NR + 255) / 256), 256, 0, stream>>>(part, f, cbs[s], idx);
        float* xout   = out + (size_t)s * ETOT;
        float* reconp = (s == 2) ? out + 3 * ETOT + 3 : nullptr;
        _Float16* fsout = (s < 2) ? fs : nullptr;
        vq_update<<<dim3(25, 16, 16), 256, 0, stream>>>(f, cbs[s], idx, xout,
                                                        out, out + ETOT, reconp,
                                                        fsout, lacc + s);
    }
    finalize_losses<<<1, 64, 0, stream>>>(lacc, out + 3 * ETOT);
}

// Round 13
// 738.008 us; speedup vs baseline: 1.1950x; 1.0006x over previous
//
#include <hip/hip_runtime.h>
#include <cstddef>

#define BB    16
#define CDIM  512
#define HWN   784
#define KC    2048
#define NR    (BB*HWN)                  // 12544 rows (= 49*256)
#define ETOT  ((size_t)BB*CDIM*HWN)     // 6422528 elements per tensor
#define NSTRIP 16                       // code strips of 128
#define TAU   0.02f
#define APL   8192                      // A plane buffer (halves) = 256*32
#define BPL   4096                      // B plane buffer (halves) = 128*32

typedef _Float16 hf8 __attribute__((ext_vector_type(8)));
typedef float f32x4 __attribute__((ext_vector_type(4)));

__device__ __forceinline__ void gload_lds16(const void* g, void* l) {
    __builtin_amdgcn_global_load_lds((const __attribute__((address_space(1))) void*)g,
                                     (__attribute__((address_space(3))) void*)l, 16, 0, 0);
}

// ---------------------------------------------------------------- utilities

// head (B,C,HW) -> f rows (fp32) AND fs split rows (f16 [hi(512)|lo(512)]);
// block (0,0,0) also zeroes the loss accumulators.
__global__ __launch_bounds__(256)
void transpose_head_split(const float* __restrict__ head, float* __restrict__ f,
                          _Float16* __restrict__ fs, float* __restrict__ lacc) {
    __shared__ float tile[32][33];
    int b = blockIdx.z, c0 = blockIdx.y * 32, h0 = blockIdx.x * 32;
    int t = threadIdx.x;
    if (b == 0 && blockIdx.y == 0 && blockIdx.x == 0 && t < 3) lacc[t] = 0.f;
    const float* src = head + (size_t)b * CDIM * HWN;
    {
        int hl = t & 31, cl0 = t >> 5;
#pragma unroll
        for (int it = 0; it < 4; ++it) {
            int cl = cl0 + it * 8;
            int hw = h0 + hl;
            if (hw < HWN) tile[cl][hl] = src[(size_t)(c0 + cl) * HWN + hw];
        }
    }
    __syncthreads();
    float* dst = f + (size_t)b * HWN * CDIM;
    _Float16* dsts = fs + (size_t)b * HWN * 1024;
    {
        int cl = t & 31, hl0 = t >> 5;
#pragma unroll
        for (int it = 0; it < 4; ++it) {
            int hl = hl0 + it * 8;
            int hw = h0 + hl;
            if (hw < HWN) {
                float v = tile[cl][hl];
                dst[(size_t)hw * CDIM + c0 + cl] = v;
                _Float16 h = (_Float16)v;
                dsts[(size_t)hw * 1024 + c0 + cl] = h;
                dsts[(size_t)hw * 1024 + 512 + c0 + cl] = (_Float16)(v - (float)h);
            }
        }
    }
}

// codebook fp32 [K][512] -> f16 split [K][1024] + ||row||^2 (one wave per row)
__global__ __launch_bounds__(256)
void split_code_norm(const float* __restrict__ src, _Float16* __restrict__ dst,
                     float* __restrict__ cnorm) {
    int tid = blockIdx.x * 256 + threadIdx.x;        // 8 elems per thread
    int row = tid >> 6, c8 = (tid & 63) * 8;
    const float* p = src + (size_t)row * CDIM + c8;
    float4 v0 = *(const float4*)p, v1 = *(const float4*)(p + 4);
    hf8 hi, lo;
    float x[8] = {v0.x, v0.y, v0.z, v0.w, v1.x, v1.y, v1.z, v1.w};
    float s = 0.f;
#pragma unroll
    for (int j = 0; j < 8; ++j) {
        _Float16 h = (_Float16)x[j];
        hi[j] = h;
        lo[j] = (_Float16)(x[j] - (float)h);
        s += x[j] * x[j];
    }
    *(hf8*)&dst[(size_t)row * 1024 + c8] = hi;
    *(hf8*)&dst[(size_t)row * 1024 + 512 + c8] = lo;
#pragma unroll
    for (int off = 32; off; off >>= 1) s += __shfl_down(s, off);
    if ((threadIdx.x & 63) == 0) cnorm[row] = s;
}

// --------------------------------------------------- MFMA argmin (3-plane)
// 256 rows x 128 codes per block, 512 threads = 8 waves (4x2 of 64x64).
// A (slow operand, L3/HBM) DOUBLE-buffered with counted vmcnt(4) — its 4
// loads stay in flight across the whole compute phase. B (L2-hot codebook
// strip) single-buffered, latency exposed (~200cy only). LDS exactly 80KB
// -> 2 blocks/CU. XCD-swizzled 1-D grid of 784 (=8*98). T5 setprio on MFMA.
__global__ __launch_bounds__(512, 4)
void argmin_fast(const _Float16* __restrict__ fs, const _Float16* __restrict__ cs,
                 const float* __restrict__ cnorm, float4* __restrict__ part) {
    __shared__ _Float16 Ah[2 * APL];
    __shared__ _Float16 Al[2 * APL];
    __shared__ _Float16 Bh[BPL];
    __shared__ _Float16 Bl[BPL];

    int t = threadIdx.x;
    int lane = t & 63, w = t >> 6;
    int wr = w >> 1, wc = w & 1;

    // XCD-aware swizzle: nwg=784=8*98, bijective chunked map (m157)
    int lin = blockIdx.x;
    int swz = (lin & 7) * 98 + (lin >> 3);
    int strip = swz & 15, rowtile = swz >> 4;
    int rb = rowtile * 256, cb = strip * 128;

    // staging: A planes rows t>>2 and 128+(t>>2) (granules t, 512+t),
    // B planes row t>>2 (granule t). LDS dest linear; source XOR-swizzled.
    int r1 = t >> 2, s1 = t & 3;
    int sg = s1 ^ ((r1 >> 1) & 3);           // (r+128)>>1 & 3 identical
    const _Float16* gA1 = fs + (size_t)(rb + r1) * 1024 + sg * 8;
    const _Float16* gA2 = fs + (size_t)(rb + 128 + r1) * 1024 + sg * 8;
    const _Float16* gB1 = cs + (size_t)(cb + r1) * 1024 + sg * 8;
    int d1 = t * 8, d2 = (512 + t) * 8;

    // fragment read addressing (plane-local); 16-row steps keep (row>>1)&3
    int frA = wr * 64 + (lane & 15);
    int frB = wc * 64 + (lane & 15);
    int fslot = lane >> 4;
    int oA = frA * 32 + (fslot ^ ((frA >> 1) & 3)) * 8;
    int oB = frB * 32 + (fslot ^ ((frB >> 1) & 3)) * 8;

    f32x4 acc[4][4];
#pragma unroll
    for (int m = 0; m < 4; ++m)
#pragma unroll
        for (int n = 0; n < 4; ++n) acc[m][n] = (f32x4)0.f;

#define STAGE_A(P, KK) do {                                                 \
        int _ko = (KK) * 32, _ba = (P) * APL;                               \
        gload_lds16(gA1 + _ko,       &Ah[_ba + d1]);                        \
        gload_lds16(gA2 + _ko,       &Ah[_ba + d2]);                        \
        gload_lds16(gA1 + _ko + 512, &Al[_ba + d1]);                        \
        gload_lds16(gA2 + _ko + 512, &Al[_ba + d2]);                        \
    } while (0)
#define STAGE_B(KK) do {                                                    \
        int _ko = (KK) * 32;                                                \
        gload_lds16(gB1 + _ko,       &Bh[d1]);                              \
        gload_lds16(gB1 + _ko + 512, &Bl[d1]);                              \
    } while (0)

    STAGE_A(0, 0);
    for (int kk = 0; kk < 16; ++kk) {
        int ba = (kk & 1) * APL;
        STAGE_B(kk);                         // B buffer free (prev end-barrier)
        if (kk < 15) {
            STAGE_A((kk + 1) & 1, kk + 1);   // A(kk+1): stays in flight
            asm volatile("s_waitcnt vmcnt(4)" ::: "memory");  // A(kk),B(kk) done
        } else {
            asm volatile("s_waitcnt vmcnt(0)" ::: "memory");
        }
        __builtin_amdgcn_s_barrier();        // all waves: cur chunk resident
        __builtin_amdgcn_sched_barrier(0);
        hf8 bh[4], bl[4];
#pragma unroll
        for (int n = 0; n < 4; ++n) {
            bh[n] = *(hf8*)&Bh[oB + n * 512];
            bl[n] = *(hf8*)&Bl[oB + n * 512];
        }
        __builtin_amdgcn_s_setprio(1);
#pragma unroll
        for (int m = 0; m < 4; ++m) {
            hf8 ah = *(hf8*)&Ah[ba + oA + m * 512];
            hf8 al = *(hf8*)&Al[ba + oA + m * 512];
#pragma unroll
            for (int n = 0; n < 4; ++n) {
                acc[m][n] = __builtin_amdgcn_mfma_f32_16x16x32_f16(ah, bh[n], acc[m][n], 0, 0, 0);
                acc[m][n] = __builtin_amdgcn_mfma_f32_16x16x32_f16(ah, bl[n], acc[m][n], 0, 0, 0);
                acc[m][n] = __builtin_amdgcn_mfma_f32_16x16x32_f16(al, bh[n], acc[m][n], 0, 0, 0);
            }
        }
        __builtin_amdgcn_s_setprio(0);
        __builtin_amdgcn_sched_barrier(0);
        __builtin_amdgcn_s_barrier();        // reads done: buffers reusable
    }
#undef STAGE_A
#undef STAGE_B

    // epilogue: msm aliased into Ah (all LDS reads done; barrier above).
    float4 (*msm)[2] = (float4(*)[2])Ah;

    // per-lane top-2 over n, butterfly over 16 cols, deposit per (row, wc).
    // D layout: col = lane&15, row = (lane>>4)*4 + i.
    int g = lane >> 4;
#pragma unroll
    for (int m = 0; m < 4; ++m)
#pragma unroll
        for (int i = 0; i < 4; ++i) {
            float v1 = 3.0e38f, v2 = 3.0e38f;
            int i1 = 0x7fffffff, i2 = 0x7fffffff;
#pragma unroll
            for (int n = 0; n < 4; ++n) {
                int kcode = cb + wc * 64 + n * 16 + (lane & 15);
                float d = fmaf(-2.f, acc[m][n][i], cnorm[kcode]);
                if (d < v1) { v2 = v1; i2 = i1; v1 = d; i1 = kcode; }
                else if (d < v2) { v2 = d; i2 = kcode; }
            }
#pragma unroll
            for (int off = 1; off < 16; off <<= 1) {
                float ov1 = __shfl_xor(v1, off, 64); int oi1 = __shfl_xor(i1, off, 64);
                float ov2 = __shfl_xor(v2, off, 64); int oi2 = __shfl_xor(i2, off, 64);
                if (ov1 < v1 || (ov1 == v1 && oi1 < i1)) {
                    float tv = v1; int ti = i1;
                    v1 = ov1; i1 = oi1; ov1 = tv; oi1 = ti;
                }
                if (ov1 < v2 || (ov1 == v2 && oi1 < i2)) { v2 = ov1; i2 = oi1; }
                if (ov2 < v2 || (ov2 == v2 && oi2 < i2)) { v2 = ov2; i2 = oi2; }
            }
            if ((lane & 15) == 0)
                msm[wr * 64 + m * 16 + g * 4 + i][wc] =
                    make_float4(v1, __int_as_float(i1), v2, __int_as_float(i2));
        }
    __syncthreads();
    if (t < 256) {
        float4 q0 = msm[t][0], q1 = msm[t][1];
        float v1 = q0.x, v2 = q0.z;
        int   i1 = __float_as_int(q0.y), i2 = __float_as_int(q0.w);
        float ov1 = q1.x, ov2 = q1.z;
        int   oi1 = __float_as_int(q1.y), oi2 = __float_as_int(q1.w);
        if (ov1 < v1 || (ov1 == v1 && oi1 < i1)) {
            float tv = v1; int ti = i1;
            v1 = ov1; i1 = oi1; ov1 = tv; oi1 = ti;
        }
        if (ov1 < v2 || (ov1 == v2 && oi1 < i2)) { v2 = ov1; i2 = oi1; }
        if (ov2 < v2 || (ov2 == v2 && oi2 < i2)) { v2 = ov2; i2 = oi2; }
        part[(size_t)strip * NR + rb + t] =
            make_float4(v1, __int_as_float(i1), v2, __int_as_float(i2));
    }
}

// combine NSTRIP partials per row; fp64 re-check when top-2 gap < TAU
__global__ __launch_bounds__(256)
void combine_fix(const float4* __restrict__ part, const float* __restrict__ f,
                 const float* __restrict__ code, int* __restrict__ idx) {
    int n = blockIdx.x * 256 + threadIdx.x;
    if (n >= NR) return;
    float bv1 = 3.0e38f, bv2 = 3.0e38f;
    int bi1 = 0x7fffffff, bi2 = 0x7fffffff;
    for (int p = 0; p < NSTRIP; ++p) {
        float4 q = part[(size_t)p * NR + n];
        float ov1 = q.x, ov2 = q.z;
        int oi1 = __float_as_int(q.y), oi2 = __float_as_int(q.w);
        if (ov1 < bv1 || (ov1 == bv1 && oi1 < bi1)) {
            float tv = bv1; int ti = bi1;
            bv1 = ov1; bi1 = oi1; ov1 = tv; oi1 = ti;
        }
        if (ov1 < bv2 || (ov1 == bv2 && oi1 < bi2)) { bv2 = ov1; bi2 = oi1; }
        if (ov2 < bv2 || (ov2 == bv2 && oi2 < bi2)) { bv2 = ov2; bi2 = oi2; }
    }
    bi1 = min(max(bi1, 0), KC - 1);
    bi2 = min(max(bi2, 0), KC - 1);
    if (bv2 - bv1 < TAU) {
        const float* fr = f + (size_t)n * CDIM;
        const float* ca = code + (size_t)bi1 * CDIM;
        const float* cb = code + (size_t)bi2 * CDIM;
        double d1 = 0.0, d2 = 0.0;
        for (int j = 0; j < CDIM; ++j) {
            double fv = fr[j], av = ca[j], bv = cb[j];
            d1 += av * av - 2.0 * fv * av;
            d2 += bv * bv - 2.0 * fv * bv;
        }
        if (d2 < d1 || (d2 == d1 && bi2 < bi1)) bi1 = bi2;
    }
    idx[n] = bi1;
}

// ------------------------------------------------------------ update stage
// Also emits f16 split of the new residual (next stage's argmin input).
__global__ __launch_bounds__(256)
void vq_update(float* __restrict__ f, const float* __restrict__ code,
               const int* __restrict__ idx, float* __restrict__ xout,
               const float* __restrict__ x1p, const float* __restrict__ x2p,
               float* __restrict__ reconp, _Float16* __restrict__ fsout,
               float* __restrict__ lacc) {
    __shared__ float qt[32][33];
    __shared__ float wsum[4];
    int b = blockIdx.z, c0 = blockIdx.y * 32, h0 = blockIdx.x * 32;
    int t = threadIdx.x;
    int tx = t & 31, ty0 = t >> 5;
    float lsum = 0.f;
#pragma unroll
    for (int it = 0; it < 4; ++it) {
        int hwl = ty0 + it * 8;
        int hw = h0 + hwl;
        float qv = 0.f;
        if (hw < HWN) {
            int n = b * HWN + hw;
            size_t fo = (size_t)n * CDIM + c0 + tx;
            float fv = f[fo];
            qv = code[(size_t)idx[n] * CDIM + c0 + tx];
            float rem = fv - qv;
            f[fo] = rem;
            lsum += rem * rem;
            if (fsout) {
                _Float16 h = (_Float16)rem;
                fsout[(size_t)n * 1024 + c0 + tx] = h;
                fsout[(size_t)n * 1024 + 512 + c0 + tx] = (_Float16)(rem - (float)h);
            }
        }
        qt[tx][hwl] = qv;
    }
    __syncthreads();
    {
        int hl = t & 31, cl0 = t >> 5;
#pragma unroll
        for (int it = 0; it < 4; ++it) {
            int cl = cl0 + it * 8;
            int hw = h0 + hl;
            if (hw < HWN) {
                size_t off = ((size_t)b * CDIM + c0 + cl) * HWN + hw;
                float qv = qt[cl][hl];
                xout[off] = qv;
                if (reconp) reconp[off] = qv + x1p[off] + x2p[off];
            }
        }
    }
#pragma unroll
    for (int off = 32; off; off >>= 1) lsum += __shfl_down(lsum, off);
    int lane = t & 63, w = t >> 6;
    if (lane == 0) wsum[w] = lsum;
    __syncthreads();
    if (t == 0) atomicAdd(lacc, wsum[0] + wsum[1] + wsum[2] + wsum[3]);
}

__global__ void finalize_losses(const float* __restrict__ lacc, float* __restrict__ out) {
    int t = threadIdx.x;
    if (t < 3) out[t] = 2.0f * lacc[t] / (float)ETOT;
}

// ------------------------------------------------------------------- launch

extern "C" void kernel_launch(void* const* d_in, const int* in_sizes, int n_in,
                              void* d_out, int out_size, void* d_ws, size_t ws_size,
                              hipStream_t stream) {
    (void)in_sizes; (void)n_in; (void)out_size; (void)ws_size;
    const float* head = (const float*)d_in[0];
    const float* cbs[3] = {(const float*)d_in[1], (const float*)d_in[2], (const float*)d_in[3]};
    float* out = (float*)d_out;
    char* ws = (char*)d_ws;

    size_t o_f = 0;
    size_t o_fs   = o_f   + ETOT * 4;
    size_t o_cs   = o_fs  + (size_t)NR * 1024 * 2;
    size_t o_part = o_cs  + (size_t)KC * 1024 * 2;
    size_t o_idx  = o_part + (size_t)NSTRIP * NR * 16;
    size_t o_cn   = o_idx + (size_t)NR * 4;
    size_t o_la   = o_cn  + (size_t)KC * 4;      // total ~58.85 MB (proven fits, R6)

    float*     f     = (float*)(ws + o_f);
    _Float16*  fs    = (_Float16*)(ws + o_fs);
    _Float16*  cspl  = (_Float16*)(ws + o_cs);
    float4*    part  = (float4*)(ws + o_part);
    int*       idx   = (int*)(ws + o_idx);
    float*     cnorm = (float*)(ws + o_cn);
    float*     lacc  = (float*)(ws + o_la);

    transpose_head_split<<<dim3(25, 16, 16), 256, 0, stream>>>(head, f, fs, lacc);
    for (int s = 0; s < 3; ++s) {
        split_code_norm<<<dim3(KC * 64 / 256), 256, 0, stream>>>(cbs[s], cspl, cnorm);
        argmin_fast<<<dim3(NSTRIP * 49), 512, 0, stream>>>(fs, cspl, cnorm, part);
        combine_fix<<<dim3((NR + 255) / 256), 256, 0, stream>>>(part, f, cbs[s], idx);
        float* xout   = out + (size_t)s * ETOT;
        float* reconp = (s == 2) ? out + 3 * ETOT + 3 : nullptr;
        _Float16* fsout = (s < 2) ? fs : nullptr;
        vq_update<<<dim3(25, 16, 16), 256, 0, stream>>>(f, cbs[s], idx, xout,
                                                        out, out + ETOT, reconp,
                                                        fsout, lacc + s);
    }
    finalize_losses<<<1, 64, 0, stream>>>(lacc, out + 3 * ETOT);
}